// Round 14
// baseline (1364.928 us; speedup 1.0000x reference)
//
#include <hip/hip_runtime.h>

#define IN_DIM 512
#define OUT_DIM 32
#define KSTEPS 10
#define ALPHA 0.1f
#define SCB 512      // scan block chunk

#define AS1 __attribute__((address_space(1)))
#define AS3 __attribute__((address_space(3)))

typedef __attribute__((ext_vector_type(8))) short short8;    // 8 bf16 (4 VGPRs)
typedef __attribute__((ext_vector_type(4))) float floatx4;   // MFMA acc
typedef _Float16 fp16x8 __attribute__((ext_vector_type(8))); // 16B packed fp16

// ---------------- degree + rank (counting sort by degree) ----------------
// Waves process 16 node-groups in lockstep; wave time ~ max degree of the 16.
// Degree-sorting makes the 16 near-equal -> divergence multiplier 1.6 -> ~1.

__global__ void k_deg(const int* __restrict__ dst, int* __restrict__ deg, int E) {
    int e = blockIdx.x * blockDim.x + threadIdx.x;
    if (e < E) atomicAdd(&deg[dst[e]], 1);
}

__global__ void k_rsqrt(const int* __restrict__ deg, float* __restrict__ dinv0, int N) {
    int i = blockIdx.x * blockDim.x + threadIdx.x;
    if (i < N) dinv0[i] = rsqrtf((float)deg[i] + 1.0f);  // +1 self-loop
}

__global__ void k_dhist(const int* __restrict__ deg, int* __restrict__ dh, int N) {
    int i = blockIdx.x * blockDim.x + threadIdx.x;
    if (i < N) {
        int b = deg[i]; if (b > 255) b = 255;
        atomicAdd(&dh[b], 1);
    }
}

__global__ __launch_bounds__(256) void k_dscan(const int* __restrict__ dh,
                                               int* __restrict__ dhoff) {
    __shared__ int s[256];
    int t = threadIdx.x;
    int v0 = dh[t];
    s[t] = v0;
    __syncthreads();
    for (int d = 1; d < 256; d <<= 1) {
        int v = (t >= d) ? s[t - d] : 0;
        __syncthreads();
        s[t] += v;
        __syncthreads();
    }
    dhoff[t] = s[t] - v0;  // exclusive
}

__global__ void k_dscatter(const int* __restrict__ deg, const int* __restrict__ dhoff,
                           int* __restrict__ dcur, int* __restrict__ perm,
                           int* __restrict__ rank, int N) {
    int i = blockIdx.x * blockDim.x + threadIdx.x;
    if (i < N) {
        int b = deg[i]; if (b > 255) b = 255;
        int pos = dhoff[b] + atomicAdd(&dcur[b], 1);
        perm[pos] = i;
        rank[i] = pos;
    }
}

// ---------------- chunked-CSR build in RANK space ----------------
// 4 gather-space buckets per dst (L2 windowing); csr entry = rank[src]*64.

__global__ void k_count4(const int* __restrict__ src, const int* __restrict__ dst,
                         const int* __restrict__ rank, int* __restrict__ cnt,
                         int E, int cdiv) {
    int e = blockIdx.x * blockDim.x + threadIdx.x;
    if (e < E) {
        int rs = rank[src[e]];
        atomicAdd(&cnt[rank[dst[e]] * 4 + rs / cdiv], 1);
    }
}

// ---------------- parallel exclusive scan (3 phases) ----------------

__global__ __launch_bounds__(SCB) void k_bsum(const int* __restrict__ v,
                                              int* __restrict__ bsum, int M) {
    __shared__ int s[SCB];
    int i = blockIdx.x * SCB + threadIdx.x;
    s[threadIdx.x] = (i < M) ? v[i] : 0;
    __syncthreads();
    for (int d = SCB / 2; d > 0; d >>= 1) {
        if (threadIdx.x < d) s[threadIdx.x] += s[threadIdx.x + d];
        __syncthreads();
    }
    if (threadIdx.x == 0) bsum[blockIdx.x] = s[0];
}

__global__ __launch_bounds__(1024) void k_bscan(const int* __restrict__ bsum,
                                                int* __restrict__ bsum_off,
                                                int* __restrict__ total_out, int NB) {
    __shared__ int s[1024];
    int t = threadIdx.x;
    s[t] = (t < NB) ? bsum[t] : 0;
    __syncthreads();
    for (int d = 1; d < 1024; d <<= 1) {
        int v = (t >= d) ? s[t - d] : 0;
        __syncthreads();
        s[t] += v;
        __syncthreads();
    }
    if (t < NB) bsum_off[t] = (t == 0) ? 0 : s[t - 1];
    if (t == 0 && total_out) *total_out = s[1023];
}

__global__ __launch_bounds__(SCB) void k_boff(const int* __restrict__ v,
                                              const int* __restrict__ bsum_off,
                                              int* __restrict__ off, int M) {
    __shared__ int s[SCB];
    int t = threadIdx.x;
    int i = blockIdx.x * SCB + t;
    int myv = (i < M) ? v[i] : 0;
    s[t] = myv;
    __syncthreads();
    for (int d = 1; d < SCB; d <<= 1) {
        int u = (t >= d) ? s[t - d] : 0;
        __syncthreads();
        s[t] += u;
        __syncthreads();
    }
    if (i < M) off[i] = bsum_off[blockIdx.x] + s[t] - myv;  // exclusive
}

__global__ void k_fill(const int* __restrict__ src, const int* __restrict__ dst,
                       const int* __restrict__ rank, const int* __restrict__ off4,
                       int* __restrict__ cur, int* __restrict__ csrI, int E, int cdiv) {
    int e = blockIdx.x * blockDim.x + threadIdx.x;
    if (e < E) {
        int rs = rank[src[e]];
        int key = rank[dst[e]] * 4 + rs / cdiv;
        int pos = off4[key] + atomicAdd(&cur[key], 1);
        csrI[pos] = rs * (OUT_DIM * 2);
    }
}

// ---------------- bf16 split helpers ----------------

__device__ inline unsigned bf16_rne(float f) {
    unsigned u = __float_as_uint(f);
    return (u + 0x7FFFu + ((u >> 16) & 1u)) >> 16;
}

__global__ void k_wsplit(const float* __restrict__ W, short* __restrict__ Wh,
                         short* __restrict__ Wl, int M) {
    int i = blockIdx.x * blockDim.x + threadIdx.x;
    if (i < M) {
        float f = W[i];
        unsigned hb = bf16_rne(f);
        float fh = __uint_as_float(hb << 16);
        unsigned lb = bf16_rne(f - fh);
        Wh[i] = (short)hb;
        Wl[i] = (short)lb;
    }
}

__device__ inline void split8v(float4 v0, float4 v1, short8& hi, short8& lo) {
    float fv[8] = {v0.x, v0.y, v0.z, v0.w, v1.x, v1.y, v1.z, v1.w};
#pragma unroll
    for (int j = 0; j < 8; j++) {
        unsigned hb = bf16_rne(fv[j]);
        float fh = __uint_as_float(hb << 16);
        unsigned lb = bf16_rne(fv[j] - fh);
        hi[j] = (short)hb;
        lo[j] = (short)lb;
    }
}

// ---------------- dense projection (gemm7, epilogue writes RANK space) ----------------

#define WAITV(n) asm volatile("s_waitcnt vmcnt(" #n ")" ::: "memory")

__global__ __launch_bounds__(256) void k_gemm7(const float* __restrict__ x,
                                               const short* __restrict__ Wh,
                                               const short* __restrict__ Wl,
                                               const float* __restrict__ bias,
                                               const float* __restrict__ dinv0,
                                               const int* __restrict__ rank,
                                               float* __restrict__ h,
                                               _Float16* __restrict__ y0,
                                               _Float16* __restrict__ hy,
                                               float* __restrict__ dinvR, int N) {
    __shared__ char lds[4][2][2048];   // [wave][buf][16 rows x 128B]
    const int t = threadIdx.x;
    const int wave = t >> 6, lane = t & 63;
    const int m = lane & 15, quad = lane >> 4;
    const int rowBase = blockIdx.x * 64 + wave * 16;

    const int srow = lane >> 3;          // 0..7
    const int sbyte = (lane & 7) * 16;   // 0..112
    long so0, so1;
    {
        int rl, r;
#define MKSO(k, v)                                                        \
        rl = 8 * (k) + srow;                                              \
        r = rowBase + rl; if (r >= N) r = N - 1;                          \
        v = (long)r * (IN_DIM * 4) + (sbyte ^ ((rl & 7) << 4));
        MKSO(0, so0) MKSO(1, so1)
#undef MKSO
    }
    const char* xb = (const char*)x;
    char* wb0 = &lds[wave][0][0];
    char* wb1 = &lds[wave][1][0];

    const int key = (m & 7) << 4;
    const int rb = m * 128;

    const short* w0h = Wh + (size_t)m * IN_DIM + quad * 8;          // outs 0..15
    const short* w0l = Wl + (size_t)m * IN_DIM + quad * 8;
    const short* w1h = Wh + (size_t)(m + 16) * IN_DIM + quad * 8;   // outs 16..31
    const short* w1l = Wl + (size_t)(m + 16) * IN_DIM + quad * 8;

    floatx4 acc0 = {0.f, 0.f, 0.f, 0.f};
    floatx4 acc1 = {0.f, 0.f, 0.f, 0.f};

#define STAGE(ch, buf) do {                                               \
        __builtin_amdgcn_global_load_lds(                                 \
            (const AS1 void*)(xb + so0 + (ch) * 128),                     \
            (AS3 void*)((buf) + 0 * 1024), 16, 0, 0);                     \
        __builtin_amdgcn_global_load_lds(                                 \
            (const AS1 void*)(xb + so1 + (ch) * 128),                     \
            (AS3 void*)((buf) + 1 * 1024), 16, 0, 0);                     \
    } while (0)

#define BLOAD(ch, P0h, P0l, P1h, P1l) do {                                \
        const int ko = (ch) * 32;                                         \
        P0h = *(const short8*)(w0h + ko);                                 \
        P0l = *(const short8*)(w0l + ko);                                 \
        P1h = *(const short8*)(w1h + ko);                                 \
        P1l = *(const short8*)(w1l + ko);                                 \
    } while (0)

#define CONSUME(buf, Bh0, Bl0, Bh1, Bl1) do {                             \
        int o0 = rb + ((quad * 32) ^ key);                                \
        int o1 = rb + ((quad * 32 + 16) ^ key);                           \
        float4 v0 = *(const float4*)((buf) + o0);                         \
        float4 v1 = *(const float4*)((buf) + o1);                         \
        short8 Ah, Al;                                                    \
        split8v(v0, v1, Ah, Al);                                          \
        acc0 = __builtin_amdgcn_mfma_f32_16x16x32_bf16(Ah, Bh0, acc0, 0, 0, 0); \
        acc1 = __builtin_amdgcn_mfma_f32_16x16x32_bf16(Ah, Bh1, acc1, 0, 0, 0); \
        acc0 = __builtin_amdgcn_mfma_f32_16x16x32_bf16(Al, Bh0, acc0, 0, 0, 0); \
        acc1 = __builtin_amdgcn_mfma_f32_16x16x32_bf16(Al, Bh1, acc1, 0, 0, 0); \
        acc0 = __builtin_amdgcn_mfma_f32_16x16x32_bf16(Ah, Bl0, acc0, 0, 0, 0); \
        acc1 = __builtin_amdgcn_mfma_f32_16x16x32_bf16(Ah, Bl1, acc1, 0, 0, 0); \
    } while (0)

    short8 p0hA, p0lA, p1hA, p1lA;   // B set A
    short8 p0hB, p0lB, p1hB, p1lB;   // B set B

    STAGE(0, wb0);
    BLOAD(0, p0hA, p0lA, p1hA, p1lA);

#define ITER_A(ch, curbuf, nextbuf)                                       \
    BLOAD((ch) + 1, p0hB, p0lB, p1hB, p1lB);                              \
    STAGE((ch) + 1, nextbuf);                                             \
    WAITV(6);                                                             \
    CONSUME(curbuf, p0hA, p0lA, p1hA, p1lA);

#define ITER_B(ch, curbuf, nextbuf)                                       \
    BLOAD((ch) + 1, p0hA, p0lA, p1hA, p1lA);                              \
    STAGE((ch) + 1, nextbuf);                                             \
    WAITV(6);                                                             \
    CONSUME(curbuf, p0hB, p0lB, p1hB, p1lB);

    ITER_A(0,  wb0, wb1)
    ITER_B(1,  wb1, wb0)
    ITER_A(2,  wb0, wb1)
    ITER_B(3,  wb1, wb0)
    ITER_A(4,  wb0, wb1)
    ITER_B(5,  wb1, wb0)
    ITER_A(6,  wb0, wb1)
    ITER_B(7,  wb1, wb0)
    ITER_A(8,  wb0, wb1)
    ITER_B(9,  wb1, wb0)
    ITER_A(10, wb0, wb1)
    ITER_B(11, wb1, wb0)
    ITER_A(12, wb0, wb1)
    ITER_B(13, wb1, wb0)
    ITER_A(14, wb0, wb1)
    WAITV(0);
    CONSUME(wb1, p0hB, p0lB, p1hB, p1lB);

#undef ITER_A
#undef ITER_B
#undef STAGE
#undef BLOAD
#undef CONSUME

    float b0 = bias[m], b1 = bias[16 + m];
#pragma unroll
    for (int rr2 = 0; rr2 < 4; rr2++) {
        int node = rowBase + quad * 4 + rr2;
        if (node < N) {
            int r = rank[node];
            float v0 = acc0[rr2] + b0;
            float v1 = acc1[rr2] + b1;
            float dv = dinv0[node];
            h[(size_t)r * OUT_DIM + m]        = v0;
            h[(size_t)r * OUT_DIM + 16 + m]   = v1;
            y0[(size_t)r * OUT_DIM + m]       = (_Float16)(dv * v0);
            y0[(size_t)r * OUT_DIM + 16 + m]  = (_Float16)(dv * v1);
            hy[(size_t)r * OUT_DIM + m]       = (_Float16)(ALPHA * dv * v0);
            hy[(size_t)r * OUT_DIM + 16 + m]  = (_Float16)(ALPHA * dv * v1);
            if (m == 0) dinvR[r] = dv;
        }
    }
}

// ---------------- propagation: rank-space pull (degree-uniform waves) ----------------
// Inner loop identical to round 13. Group g handles rank-space node g; the
// 16 groups of a wave have near-equal degree -> no lockstep divergence.
// Final step scatters fp32 z to d_out at perm[g].

__global__ __launch_bounds__(256) void k_pull(const int* __restrict__ off4,
                                              const int* __restrict__ csrI,
                                              const _Float16* __restrict__ yprev,
                                              const _Float16* __restrict__ hy,
                                              const float* __restrict__ h,
                                              const float* __restrict__ dinvR,
                                              const int* __restrict__ perm,
                                              _Float16* __restrict__ ynext,
                                              float* __restrict__ outF, int N) {
    int t = blockIdx.x * 256 + threadIdx.x;
    int g = t >> 2;
    int l = (t & 3) * 8;
    if (g >= N) return;
    int beg = off4[g * 4];
    int end = off4[g * 4 + 4];
    const char* zb = (const char*)yprev + l * 2;

    float a0[8], a1[8];
#pragma unroll
    for (int c = 0; c < 8; c++) { a0[c] = 0.f; a1[c] = 0.f; }

#define ONE_EDGE(J, A) do {                                                   \
        fp16x8 z_ = *(const fp16x8*)(zb + csrI[J]);                           \
        _Pragma("unroll")                                                     \
        for (int c = 0; c < 8; c++) A[c] += (float)z_[c];                     \
    } while (0)

#define GATHER8(C0, C1) do {                                                  \
        fp16x8 z0 = *(const fp16x8*)(zb + (C0).x);                            \
        fp16x8 z1 = *(const fp16x8*)(zb + (C0).y);                            \
        fp16x8 z2 = *(const fp16x8*)(zb + (C0).z);                            \
        fp16x8 z3 = *(const fp16x8*)(zb + (C0).w);                            \
        fp16x8 z4 = *(const fp16x8*)(zb + (C1).x);                            \
        fp16x8 z5 = *(const fp16x8*)(zb + (C1).y);                            \
        fp16x8 z6 = *(const fp16x8*)(zb + (C1).z);                            \
        fp16x8 z7 = *(const fp16x8*)(zb + (C1).w);                            \
        _Pragma("unroll")                                                     \
        for (int c = 0; c < 8; c++) {                                         \
            a0[c] += (float)z0[c];                                            \
            a1[c] += (float)z1[c];                                            \
            a0[c] += (float)z2[c];                                            \
            a1[c] += (float)z3[c];                                            \
            a0[c] += (float)z4[c];                                            \
            a1[c] += (float)z5[c];                                            \
            a0[c] += (float)z6[c];                                            \
            a1[c] += (float)z7[c];                                            \
        }                                                                     \
    } while (0)

    int j = beg;
    while ((j & 3) && j < end) { ONE_EDGE(j, a0); j++; }
    int nb = (end - j) >> 3;   // count of 8-edge blocks
    if (nb > 0) {
        int4 c0 = *(const int4*)(csrI + j);
        int4 c1 = *(const int4*)(csrI + j + 4);
        for (int b = 1; b < nb; b++) {
            int4 n0 = *(const int4*)(csrI + j + 8 * b);
            int4 n1 = *(const int4*)(csrI + j + 8 * b + 4);
            GATHER8(c0, c1);
            c0 = n0; c1 = n1;
        }
        GATHER8(c0, c1);
        j += 8 * nb;
    }
    if (end - j >= 4) {
        int4 c0 = *(const int4*)(csrI + j);
        fp16x8 z0 = *(const fp16x8*)(zb + c0.x);
        fp16x8 z1 = *(const fp16x8*)(zb + c0.y);
        fp16x8 z2 = *(const fp16x8*)(zb + c0.z);
        fp16x8 z3 = *(const fp16x8*)(zb + c0.w);
#pragma unroll
        for (int c = 0; c < 8; c++) {
            a0[c] += (float)z0[c];
            a1[c] += (float)z1[c];
            a0[c] += (float)z2[c];
            a1[c] += (float)z3[c];
        }
        j += 4;
    }
    for (; j < end; j++) ONE_EDGE(j, a0);
#undef ONE_EDGE
#undef GATHER8

    float d = dinvR[g];
    fp16x8 ys = *(const fp16x8*)((const char*)yprev + (size_t)g * (OUT_DIM * 2) + l * 2);
    if (outF) {
        float od = (1.0f - ALPHA) * d;
        float4 h0 = *(const float4*)(h + (size_t)g * OUT_DIM + l);
        float4 h1 = *(const float4*)(h + (size_t)g * OUT_DIM + l + 4);
        float hh[8] = {h0.x, h0.y, h0.z, h0.w, h1.x, h1.y, h1.z, h1.w};
        float rr[8];
#pragma unroll
        for (int c = 0; c < 8; c++) {
            float s = (a0[c] + a1[c]) + (float)ys[c];
            rr[c] = fmaf(od, s, ALPHA * hh[c]);
        }
        int n0 = perm[g];   // scatter to original node order
        *(float4*)(outF + (size_t)n0 * OUT_DIM + l)     = make_float4(rr[0], rr[1], rr[2], rr[3]);
        *(float4*)(outF + (size_t)n0 * OUT_DIM + l + 4) = make_float4(rr[4], rr[5], rr[6], rr[7]);
    } else {
        float og = (1.0f - ALPHA) * d * d;
        fp16x8 hyv = *(const fp16x8*)((const char*)hy + (size_t)g * (OUT_DIM * 2) + l * 2);
        fp16x8 o;
#pragma unroll
        for (int c = 0; c < 8; c++) {
            float s = (a0[c] + a1[c]) + (float)ys[c];
            o[c] = (_Float16)fmaf(og, s, (float)hyv[c]);
        }
        *(fp16x8*)(ynext + (size_t)g * OUT_DIM + l) = o;
    }
}

extern "C" void kernel_launch(void* const* d_in, const int* in_sizes, int n_in,
                              void* d_out, int out_size, void* d_ws, size_t ws_size,
                              hipStream_t stream) {
    const float* x    = (const float*)d_in[0];
    const float* W    = (const float*)d_in[1];
    const float* bias = (const float*)d_in[2];
    const int*   ei   = (const int*)d_in[3];

    const int N = in_sizes[0] / IN_DIM;   // 100000
    const int E = in_sizes[3] / 2;        // 1600000
    const int* src = ei;
    const int* dst = ei + E;
    const int cdiv = (N + 3) / 4;
    const int M = 4 * N;                  // scan length
    const int NB = (M + SCB - 1) / SCB;   // 782 <= 1024
    const int WM = OUT_DIM * IN_DIM;      // 16384

    // workspace layout (each offset 16B-aligned; deg..dcur contiguous for one memset)
    char* ws = (char*)d_ws;
    size_t o = 0;
#define ALLOC(ptr, type, bytes)                         \
    type* ptr = (type*)(ws + o); o += (size_t)(bytes); o = (o + 15) & ~(size_t)15;
    ALLOC(h,     float,    (size_t)N * OUT_DIM * 4)   // 12.8 MB (rank space)
    ALLOC(yA,    _Float16, (size_t)N * OUT_DIM * 2)   // 6.4 MB
    ALLOC(yB,    _Float16, (size_t)N * OUT_DIM * 2)   // 6.4 MB
    ALLOC(hy,    _Float16, (size_t)N * OUT_DIM * 2)   // 6.4 MB
    ALLOC(csrI,  int,      (size_t)E * 4)             // 6.4 MB
    ALLOC(dinv0, float,    (size_t)N * 4)
    ALLOC(dinvR, float,    (size_t)N * 4)
    ALLOC(perm,  int,      (size_t)N * 4)
    ALLOC(rank,  int,      (size_t)N * 4)
    ALLOC(off4,  int,      (size_t)(M + 1) * 4)
    ALLOC(dhoff, int,      256 * 4)
    ALLOC(bsum,  int,      (size_t)NB * 4)
    ALLOC(boff,  int,      (size_t)NB * 4)
    ALLOC(Wh,    short,    (size_t)WM * 2)
    ALLOC(Wl,    short,    (size_t)WM * 2)
    // zeroed region (contiguous): deg[N], cnt[M], cur[M], dh[256], dcur[256]
    ALLOC(deg,   int,      (size_t)N * 4)
    ALLOC(cnt,   int,      (size_t)M * 4)
    ALLOC(cur,   int,      (size_t)M * 4)
    ALLOC(dh,    int,      256 * 4)
    ALLOC(dcur,  int,      256 * 4)
#undef ALLOC

    const int B = 256;
    int gN = (N + B - 1) / B;
    int gE = (E + B - 1) / B;
    int gP = ((size_t)N * 4 + B - 1) / B;   // pull grid (1563)
    int gG = (N + 63) / 64;                 // gemm grid (1563)
    int gW = (WM + B - 1) / B;

    hipMemsetAsync(deg, 0, (size_t)(N + 2 * M + 512) * 4, stream);

    // degree -> norm + counting sort (perm, rank)
    k_deg<<<gE, B, 0, stream>>>(dst, deg, E);
    k_rsqrt<<<gN, B, 0, stream>>>(deg, dinv0, N);
    k_dhist<<<gN, B, 0, stream>>>(deg, dh, N);
    k_dscan<<<1, 256, 0, stream>>>(dh, dhoff);
    k_dscatter<<<gN, B, 0, stream>>>(deg, dhoff, dcur, perm, rank, N);

    // chunked CSR in rank space
    k_count4<<<gE, B, 0, stream>>>(src, dst, rank, cnt, E, cdiv);
    k_bsum<<<NB, SCB, 0, stream>>>(cnt, bsum, M);
    k_bscan<<<1, 1024, 0, stream>>>(bsum, boff, off4 + M, NB);
    k_boff<<<NB, SCB, 0, stream>>>(cnt, boff, off4, M);
    k_fill<<<gE, B, 0, stream>>>(src, dst, rank, off4, cur, csrI, E, cdiv);

    // W bf16-split + dense projection (rank-space h fp32, y0, hy, dinvR)
    k_wsplit<<<gW, B, 0, stream>>>(W, Wh, Wl, WM);
    k_gemm7<<<gG, B, 0, stream>>>(x, Wh, Wl, bias, dinv0, rank, h, yA, hy, dinvR, N);

    // K propagation steps in rank space; final step scatters fp32 z to d_out
    for (int s = 0; s < KSTEPS; s++) {
        const _Float16* yprev = (s % 2 == 0) ? yA : yB;
        _Float16* ynext = (s % 2 == 0) ? yB : yA;
        float* outF = (s == KSTEPS - 1) ? (float*)d_out : nullptr;
        k_pull<<<gP, B, 0, stream>>>(off4, csrI, yprev, hy, h, dinvR, perm,
                                     ynext, outF, N);
    }
}